// Round 1
// baseline (778.330 us; speedup 1.0000x reference)
//
#include <hip/hip_runtime.h>
#include <hip/hip_bf16.h>
#include <math.h>

#define NN 512
#define HH 32
#define PP 64
#define EE 512

// ---------------------------------------------------------------------------
// Kernel 0: prep small derived params
//   Wu[h][e]  = sum_d Wf[h*16+d] * Wv[h*16+d][e]          (32x512)
//   Wbp[h][p] = ln_p_g[p] * Wb[h][p]                      (32x64)
//   s1[h] = sum_p ln_p_g[p]*Wb[h][p]
//   s2[h] = sum_p ln_p_b[p]*Wb[h][p] + bb[h]
// ---------------------------------------------------------------------------
__global__ __launch_bounds__(256)
void prep_kernel(const float* __restrict__ Wv, const float* __restrict__ Wf,
                 const float* __restrict__ Wb, const float* __restrict__ pg,
                 const float* __restrict__ pb, const float* __restrict__ bbv,
                 float* __restrict__ Wu, float* __restrict__ Wbp,
                 float* __restrict__ s1, float* __restrict__ s2) {
    const int t = threadIdx.x;
    for (int o = t; o < HH * EE; o += 256) {
        const int h = o >> 9, e = o & 511;
        float acc = 0.f;
#pragma unroll
        for (int d = 0; d < 16; ++d)
            acc += Wf[h * 16 + d] * Wv[(size_t)(h * 16 + d) * EE + e];
        Wu[o] = acc;
    }
    for (int o = t; o < HH * PP; o += 256) {
        const int p = o & 63;
        Wbp[o] = pg[p] * Wb[o];
    }
    if (t < HH) {
        float a = 0.f, s = 0.f;
#pragma unroll
        for (int p = 0; p < PP; ++p) {
            a += pg[p] * Wb[t * PP + p];
            s += pb[p] * Wb[t * PP + p];
        }
        s1[t] = a;
        s2[t] = s + bbv[t];
    }
}

// ---------------------------------------------------------------------------
// Kernel 1: LayerNorm(query) -> xq   (2048 rows of 512)
// ---------------------------------------------------------------------------
__global__ __launch_bounds__(256)
void ln_query_kernel(const float* __restrict__ x, const float* __restrict__ g,
                     const float* __restrict__ b, float* __restrict__ xq) {
    const int row = blockIdx.x;
    const int t = threadIdx.x;
    const int wave = t >> 6, lane = t & 63;
    const float2 v = ((const float2*)(x + (size_t)row * EE))[t];
    float s = v.x + v.y;
    float ss = v.x * v.x + v.y * v.y;
#pragma unroll
    for (int o = 32; o > 0; o >>= 1) {
        s += __shfl_xor(s, o, 64);
        ss += __shfl_xor(ss, o, 64);
    }
    __shared__ float rs[4], rss[4];
    if (lane == 0) { rs[wave] = s; rss[wave] = ss; }
    __syncthreads();
    s = rs[0] + rs[1] + rs[2] + rs[3];
    ss = rss[0] + rss[1] + rss[2] + rss[3];
    const float mu = s * (1.f / 512.f);
    const float var = ss * (1.f / 512.f) - mu * mu;
    const float istd = rsqrtf(var + 1e-5f);
    const float2 gg = ((const float2*)g)[t];
    const float2 bb2 = ((const float2*)b)[t];
    float2 o;
    o.x = (v.x - mu) * istd * gg.x + bb2.x;
    o.y = (v.y - mu) * istd * gg.y + bb2.y;
    ((float2*)(xq + (size_t)row * EE))[t] = o;
}

// ---------------------------------------------------------------------------
// Kernel 2: projections GEMM.  C[2048 x 1056] = xq @ [Wq|Wk|Wu]^T
//   cols [0,512)    -> q  (scaled by 0.25), stored [row][e]
//   cols [512,1024) -> k, stored [row][e]
//   cols [1024,1056)-> u, stored [row][h]
// 64x64 tile, BK=16, 256 threads, 4x4 micro-tile.
// ---------------------------------------------------------------------------
__global__ __launch_bounds__(256)
void proj_gemm_kernel(const float* __restrict__ xq, const float* __restrict__ Wq,
                      const float* __restrict__ Wk, const float* __restrict__ Wu,
                      float* __restrict__ qo, float* __restrict__ ko,
                      float* __restrict__ uo) {
    __shared__ float As[16][68];
    __shared__ float Bs[16][68];
    const int t = threadIdx.x;
    const int row0 = blockIdx.x * 64;
    const int col0 = blockIdx.y * 64;
    const int tx = t & 15, ty = t >> 4;
    const int lr = t >> 2, lk = (t & 3) << 2;

    // W row pointer for this thread's B-tile row (global col = col0+lr)
    const int gcb = col0 + lr;
    const float* wrow = nullptr;
    if (gcb < 512) wrow = Wq + (size_t)gcb * EE;
    else if (gcb < 1024) wrow = Wk + (size_t)(gcb - 512) * EE;
    else if (gcb < 1056) wrow = Wu + (size_t)(gcb - 1024) * EE;

    float acc[4][4] = {};
    for (int k0 = 0; k0 < EE; k0 += 16) {
        const float4 av = *(const float4*)(xq + (size_t)(row0 + lr) * EE + k0 + lk);
        float4 bv = make_float4(0.f, 0.f, 0.f, 0.f);
        if (wrow) bv = *(const float4*)(wrow + k0 + lk);
        __syncthreads();
        As[lk + 0][lr] = av.x; As[lk + 1][lr] = av.y;
        As[lk + 2][lr] = av.z; As[lk + 3][lr] = av.w;
        Bs[lk + 0][lr] = bv.x; Bs[lk + 1][lr] = bv.y;
        Bs[lk + 2][lr] = bv.z; Bs[lk + 3][lr] = bv.w;
        __syncthreads();
#pragma unroll
        for (int kk = 0; kk < 16; ++kk) {
            const float4 a = *(const float4*)&As[kk][ty * 4];
            const float4 b = *(const float4*)&Bs[kk][tx * 4];
            acc[0][0] += a.x * b.x; acc[0][1] += a.x * b.y; acc[0][2] += a.x * b.z; acc[0][3] += a.x * b.w;
            acc[1][0] += a.y * b.x; acc[1][1] += a.y * b.y; acc[1][2] += a.y * b.z; acc[1][3] += a.y * b.w;
            acc[2][0] += a.z * b.x; acc[2][1] += a.z * b.y; acc[2][2] += a.z * b.z; acc[2][3] += a.z * b.w;
            acc[3][0] += a.w * b.x; acc[3][1] += a.w * b.y; acc[3][2] += a.w * b.z; acc[3][3] += a.w * b.w;
        }
    }
#pragma unroll
    for (int r = 0; r < 4; ++r) {
        const int grow = row0 + ty * 4 + r;
#pragma unroll
        for (int cc = 0; cc < 4; ++cc) {
            const int gc = col0 + tx * 4 + cc;
            const float v = acc[r][cc];
            if (gc < 512) qo[(size_t)grow * EE + gc] = v * 0.25f;
            else if (gc < 1024) ko[(size_t)grow * EE + (gc - 512)] = v;
            else if (gc < 1056) uo[(size_t)grow * HH + (gc - 1024)] = v;
        }
    }
}

// ---------------------------------------------------------------------------
// Kernel 3: main fused attention+force kernel. One block per (c,i).
//  Phase A: attn[h][j] = q_i . k_j (per head) + pair-LN bias   (LDS 32x512)
//  Phase B: per-head softmax over j (max/exp/sum, wave-parallel)
//  Phase C: w[j] = sum_h p[h][j]*u[j][h]/den[h];  force_r = sum_j w[j]*delta_r
// ---------------------------------------------------------------------------
__global__ __launch_bounds__(256, 2)
void attn_force_kernel(const float* __restrict__ pair, const float* __restrict__ delta,
                       const float* __restrict__ qws, const float* __restrict__ kws,
                       const float* __restrict__ uws, const float* __restrict__ Wbp,
                       const float* __restrict__ s1, const float* __restrict__ s2,
                       float* __restrict__ out) {
    __shared__ float attn[HH * NN];   // 64 KB
    __shared__ float invden[HH];
    __shared__ float red[12];

    const int t = threadIdx.x;
    const int wave = t >> 6, lane = t & 63;
    const int bid = blockIdx.x;         // c*512 + i
    const int c = bid >> 9;
    const int i = bid & 511;

    const float4* qrow = (const float4*)(qws + (size_t)bid * EE);  // uniform -> s_load

    // ---------------- Phase A ----------------
    for (int jr = 0; jr < 2; ++jr) {
        const int j = jr * 256 + t;
        const float4* prow =
            (const float4*)(pair + (((size_t)c * NN + i) * NN + j) * PP);
        float4 pv[16];
#pragma unroll
        for (int x = 0; x < 16; ++x) pv[x] = prow[x];
        float s = 0.f, ss = 0.f;
#pragma unroll
        for (int x = 0; x < 16; ++x) {
            s += pv[x].x + pv[x].y + pv[x].z + pv[x].w;
            ss += pv[x].x * pv[x].x + pv[x].y * pv[x].y +
                  pv[x].z * pv[x].z + pv[x].w * pv[x].w;
        }
        const float mu = s * (1.f / 64.f);
        const float var = ss * (1.f / 64.f) - mu * mu;
        const float istd = rsqrtf(var + 1e-5f);
        const float4* krow = (const float4*)(kws + ((size_t)c * NN + j) * EE);
#pragma unroll 4
        for (int h = 0; h < HH; ++h) {
            const float4* wb = (const float4*)(Wbp + h * PP);  // uniform -> s_load
            float acc = 0.f;
#pragma unroll
            for (int x = 0; x < 16; ++x) {
                const float4 w = wb[x];
                acc += pv[x].x * w.x + pv[x].y * w.y + pv[x].z * w.z + pv[x].w * w.w;
            }
            float qk = 0.f;
#pragma unroll
            for (int d = 0; d < 4; ++d) {
                const float4 kv = krow[h * 4 + d];
                const float4 qv = qrow[h * 4 + d];
                qk += kv.x * qv.x + kv.y * qv.y + kv.z * qv.z + kv.w * qv.w;
            }
            attn[h * NN + j] = qk + istd * (acc - mu * s1[h]) + s2[h];
        }
    }
    __syncthreads();

    // ---------------- Phase B: softmax per head ----------------
#pragma unroll
    for (int hh = 0; hh < 8; ++hh) {
        const int h = wave * 8 + hh;
        float m = -1e30f;
#pragma unroll
        for (int x = 0; x < 8; ++x) m = fmaxf(m, attn[h * NN + x * 64 + lane]);
#pragma unroll
        for (int o = 32; o > 0; o >>= 1) m = fmaxf(m, __shfl_xor(m, o, 64));
        float sum = 0.f;
#pragma unroll
        for (int x = 0; x < 8; ++x) {
            const float p = __expf(attn[h * NN + x * 64 + lane] - m);
            attn[h * NN + x * 64 + lane] = p;
            sum += p;
        }
#pragma unroll
        for (int o = 32; o > 0; o >>= 1) sum += __shfl_xor(sum, o, 64);
        if (lane == 0) invden[h] = 1.f / sum;
    }
    __syncthreads();

    // ---------------- Phase C: weights + force ----------------
    float fx = 0.f, fy = 0.f, fz = 0.f;
    for (int jr = 0; jr < 2; ++jr) {
        const int j = jr * 256 + t;
        const float4* urow = (const float4*)(uws + ((size_t)c * NN + j) * HH);
        float w = 0.f;
#pragma unroll
        for (int x = 0; x < 8; ++x) {
            const float4 uv = urow[x];
            const int h0 = x * 4;
            w += attn[(h0 + 0) * NN + j] * uv.x * invden[h0 + 0];
            w += attn[(h0 + 1) * NN + j] * uv.y * invden[h0 + 1];
            w += attn[(h0 + 2) * NN + j] * uv.z * invden[h0 + 2];
            w += attn[(h0 + 3) * NN + j] * uv.w * invden[h0 + 3];
        }
        const float* dp = delta + (((size_t)c * NN + i) * NN + j) * 3;
        fx += w * dp[0];
        fy += w * dp[1];
        fz += w * dp[2];
    }
#pragma unroll
    for (int o = 32; o > 0; o >>= 1) {
        fx += __shfl_xor(fx, o, 64);
        fy += __shfl_xor(fy, o, 64);
        fz += __shfl_xor(fz, o, 64);
    }
    if (lane == 0) {
        red[wave * 3 + 0] = fx;
        red[wave * 3 + 1] = fy;
        red[wave * 3 + 2] = fz;
    }
    __syncthreads();
    if (t == 0) {
        out[(size_t)bid * 3 + 0] = red[0] + red[3] + red[6] + red[9];
        out[(size_t)bid * 3 + 1] = red[1] + red[4] + red[7] + red[10];
        out[(size_t)bid * 3 + 2] = red[2] + red[5] + red[8] + red[11];
    }
}

// ---------------------------------------------------------------------------
extern "C" void kernel_launch(void* const* d_in, const int* in_sizes, int n_in,
                              void* d_out, int out_size, void* d_ws, size_t ws_size,
                              hipStream_t stream) {
    const float* query   = (const float*)d_in[0];
    const float* pair    = (const float*)d_in[1];
    const float* delta   = (const float*)d_in[2];
    const float* ln_q_g  = (const float*)d_in[3];
    const float* ln_q_b  = (const float*)d_in[4];
    const float* ln_p_g  = (const float*)d_in[5];
    const float* ln_p_b  = (const float*)d_in[6];
    const float* Wq      = (const float*)d_in[7];
    const float* Wk      = (const float*)d_in[8];
    const float* Wv      = (const float*)d_in[9];
    const float* Wb      = (const float*)d_in[10];
    const float* bbv     = (const float*)d_in[11];
    const float* Wf      = (const float*)d_in[12];
    float* out = (float*)d_out;

    float* ws = (float*)d_ws;
    float* xq  = ws;                        // 2048*512
    float* qws = xq + 2048 * 512;           // 2048*512
    float* kws = qws + 2048 * 512;          // 2048*512
    float* uws = kws + 2048 * 512;          // 2048*32
    float* Wu  = uws + 2048 * 32;           // 32*512
    float* Wbp = Wu + 32 * 512;             // 32*64
    float* s1  = Wbp + 32 * 64;             // 32
    float* s2  = s1 + 32;                   // 32

    prep_kernel<<<1, 256, 0, stream>>>(Wv, Wf, Wb, ln_p_g, ln_p_b, bbv,
                                       Wu, Wbp, s1, s2);
    ln_query_kernel<<<2048, 256, 0, stream>>>(query, ln_q_g, ln_q_b, xq);
    proj_gemm_kernel<<<dim3(32, 17), 256, 0, stream>>>(xq, Wq, Wk, Wu,
                                                       qws, kws, uws);
    attn_force_kernel<<<2048, 256, 0, stream>>>(pair, delta, qws, kws, uws,
                                                Wbp, s1, s2, out);
}